// Round 16
// baseline (260.003 us; speedup 1.0000x reference)
//
#include <hip/hip_runtime.h>
#include <hip/hip_bf16.h>

#define NT 4096      // H*W
#define CF 256       // feature channels
// CQK = 64

typedef __attribute__((ext_vector_type(8))) short bf16x8;
typedef __attribute__((ext_vector_type(4))) float f32x4;
typedef __attribute__((ext_vector_type(4))) short s16x4;

__device__ __forceinline__ short f2bf(float f) {
  union { float f; unsigned u; } v; v.f = f;
  unsigned r = v.u + 0x7FFFu + ((v.u >> 16) & 1u);   // RTNE
  return (short)(r >> 16);
}
__device__ __forceinline__ float bf2f(short s) {
  union { unsigned u; float f; } w; w.u = ((unsigned)(unsigned short)s) << 16;
  return w.f;
}

// async global->LDS, 16B per lane; LDS dest = wave-uniform base + lane*16
__device__ __forceinline__ void glds16(const void* g, void* l) {
  __builtin_amdgcn_global_load_lds(
      (const __attribute__((address_space(1))) void*)g,
      (__attribute__((address_space(3))) void*)l, 16, 0, 0);
}

// bare hardware exp2 (log2-domain scores shifted to <= ~0; finite args)
__device__ __forceinline__ float fexp2(float x) {
  float r;
  asm("v_exp_f32 %0, %1" : "=v"(r) : "v"(x));
  return r;
}

// ---------------------------------------------------------------------------
// Fused projections (one launch, role by blockIdx.z):
// z=0: Q (B,NT,64) = (src.w_src + b)*qscale, + per-row squared norm qnorm2.
// z=1: K (B,NT,64), Vt (B,256,NT) from ONE staging of ref, + kmax2[b].
// ---------------------------------------------------------------------------
__global__ __launch_bounds__(256, 2)
void proj_kernel(const float* __restrict__ src, const float* __restrict__ ref,
                 const float* __restrict__ w_src, const float* __restrict__ b_src,
                 const float* __restrict__ w_ref, const float* __restrict__ b_ref,
                 const float* __restrict__ w_gate, const float* __restrict__ b_gate,
                 short* __restrict__ Qw, short* __restrict__ Kw, short* __restrict__ Vw,
                 float* __restrict__ qnorm2, unsigned* __restrict__ kmax2, float qscale)
{
  __shared__ alignas(16) short Xlds[64 * 256];   // 32KB; reused as norm scratch
  const int tid = threadIdx.x;
  const int wv = tid >> 6, l = tid & 63;
  const int l15 = l & 15, l4 = l >> 4;
  const int i0 = blockIdx.x * 64;
  const int b  = blockIdx.y;
  const bool isref = (blockIdx.z != 0);
  const float* Xb = (isref ? ref : src) + (size_t)b * CF * NT;

#pragma unroll
  for (int it = 0; it < 16; ++it) {
    int c0 = it * 16 + wv * 4;
    float x0 = Xb[(size_t)(c0 + 0) * NT + i0 + l];
    float x1 = Xb[(size_t)(c0 + 1) * NT + i0 + l];
    float x2 = Xb[(size_t)(c0 + 2) * NT + i0 + l];
    float x3 = Xb[(size_t)(c0 + 3) * NT + i0 + l];
    s16x4 pk; pk[0] = f2bf(x0); pk[1] = f2bf(x1); pk[2] = f2bf(x2); pk[3] = f2bf(x3);
    int phys = (l * 512 + c0 * 2) ^ ((l & 31) << 4);
    *(s16x4*)((char*)Xlds + phys) = pk;
  }
  __syncthreads();

  if (!isref) {
    // ---- Q projection + qnorm2 ----
    f32x4 acc[4] = {};
    const int o = wv * 16 + l15;
#pragma unroll
    for (int kk = 0; kk < 8; ++kk) {
      bf16x8 a[4];
#pragma unroll
      for (int mi = 0; mi < 4; ++mi) {
        int i = 16 * mi + l15;
        int phys = (i * 512 + kk * 64 + l4 * 16) ^ ((i & 31) << 4);
        a[mi] = *(const bf16x8*)((const char*)Xlds + phys);
      }
      const float* wp = w_src + (size_t)o * CF + kk * 32 + l4 * 8;
      bf16x8 wf;
#pragma unroll
      for (int t = 0; t < 8; ++t) wf[t] = f2bf(wp[t]);
#pragma unroll
      for (int mi = 0; mi < 4; ++mi)
        acc[mi] = __builtin_amdgcn_mfma_f32_16x16x32_bf16(a[mi], wf, acc[mi], 0, 0, 0);
    }
    __syncthreads();                         // all waves done reading Xlds
    float* nlds = (float*)(void*)Xlds;       // [64][65] padded sq matrix
    const float bv = b_src[o];
#pragma unroll
    for (int mi = 0; mi < 4; ++mi)
#pragma unroll
      for (int r = 0; r < 4; ++r) {
        float val = (acc[mi][r] + bv) * qscale;
        short sv = f2bf(val);
        int row = 16 * mi + l4 * 4 + r;
        Qw[((size_t)b * NT + i0 + row) * 64 + o] = sv;
        float qr = bf2f(sv);
        nlds[row * 65 + o] = qr * qr;
      }
    __syncthreads();
    if (tid < 64) {
      float ss = 0.f;
#pragma unroll 8
      for (int j = 0; j < 64; ++j) ss += nlds[tid * 65 + j];
      qnorm2[(size_t)b * NT + i0 + tid] = ss;
    }
  } else {
    // ---- K + V projections + kmax2 ----
    f32x4 accK[4] = {};
    f32x4 accV[4][4] = {};
    const int oK = wv * 16 + l15;
#pragma unroll
    for (int kk = 0; kk < 8; ++kk) {
      bf16x8 a[4];
#pragma unroll
      for (int mi = 0; mi < 4; ++mi) {
        int i = 16 * mi + l15;
        int phys = (i * 512 + kk * 64 + l4 * 16) ^ ((i & 31) << 4);
        a[mi] = *(const bf16x8*)((const char*)Xlds + phys);
      }
      {
        const float* wp = w_ref + (size_t)oK * CF + kk * 32 + l4 * 8;
        bf16x8 wf;
#pragma unroll
        for (int t = 0; t < 8; ++t) wf[t] = f2bf(wp[t]);
#pragma unroll
        for (int mi = 0; mi < 4; ++mi)
          accK[mi] = __builtin_amdgcn_mfma_f32_16x16x32_bf16(a[mi], wf, accK[mi], 0, 0, 0);
      }
#pragma unroll
      for (int no = 0; no < 4; ++no) {
        int oV = wv * 64 + 16 * no + l15;
        const float* wp = w_gate + (size_t)oV * CF + kk * 32 + l4 * 8;
        bf16x8 wf;
#pragma unroll
        for (int t = 0; t < 8; ++t) wf[t] = f2bf(wp[t]);
#pragma unroll
        for (int mi = 0; mi < 4; ++mi)
          accV[mi][no] = __builtin_amdgcn_mfma_f32_16x16x32_bf16(a[mi], wf, accV[mi][no], 0, 0, 0);
      }
    }

#pragma unroll
    for (int no = 0; no < 4; ++no) {
      int oV = wv * 64 + 16 * no + l15;
      float bv = b_gate[oV];
#pragma unroll
      for (int mi = 0; mi < 4; ++mi) {
        s16x4 pk;
#pragma unroll
        for (int r = 0; r < 4; ++r) pk[r] = f2bf(accV[mi][no][r] + bv);
        *(s16x4*)&Vw[((size_t)b * CF + oV) * NT + i0 + 16 * mi + l4 * 4] = pk;
      }
    }

    __syncthreads();                         // all waves done reading Xlds
    float* nlds = (float*)(void*)Xlds;       // [64][65]
    const float bk = b_ref[oK];
#pragma unroll
    for (int mi = 0; mi < 4; ++mi)
#pragma unroll
      for (int r = 0; r < 4; ++r) {
        float val = accK[mi][r] + bk;
        short sv = f2bf(val);
        int row = 16 * mi + l4 * 4 + r;
        Kw[((size_t)b * NT + i0 + row) * 64 + oK] = sv;
        float qr = bf2f(sv);
        nlds[row * 65 + oK] = qr * qr;
      }
    __syncthreads();
    if (tid < 64) {
      float ss = 0.f;
#pragma unroll 8
      for (int j = 0; j < 64; ++j) ss += nlds[tid * 65 + j];
#pragma unroll
      for (int m = 1; m <= 32; m <<= 1) ss = fmaxf(ss, __shfl_xor(ss, m, 64));
      if (tid == 0) atomicMax(&kmax2[b], __float_as_uint(ss));
    }
  }
}

// ---------------------------------------------------------------------------
// Flash attention partials.  LDS-staged K/V (global_load_lds, dbuf).
// KEY-SPLIT ACROSS WGs: grid = 32 qt x 2 z x 2 ks x 4 b = 512 wgs of 512thr
// -> 2 wg/CU = 16 waves/CU = 4 waves/SIMD (the latency-hiding lever; all
// 2-wave/SIMD variants plateaued at ~40 cyc/key).
// wg = 8 waves = 128 q-rows x 128 cols x 2048 keys (ks half); wave = 16x128.
// Combine: unnormalized O and row-sum l via f32 atomicAdd -- exactly 2
// contributors per element, f32 add commutative -> bit-deterministic.
// STATIC softmax shift (Cauchy-Schwarz) folded into QK C-init.
// Arena 48KB: K dbuf 2x8KB at 0; V dbuf 2x16KB at 16384; epilogue reuse.
// ---------------------------------------------------------------------------
__global__ __launch_bounds__(512, 4)
void flash_kernel(const short* __restrict__ Q, const short* __restrict__ K,
                  const short* __restrict__ Vt,
                  const float* __restrict__ qnorm2, const unsigned* __restrict__ kmax2,
                  float* __restrict__ Opart, float* __restrict__ lpart)
{
  __shared__ alignas(16) char arena[49152];

  const int tid = threadIdx.x;
  const int wv = tid >> 6, l = tid & 63;     // wv = 0..7
  const int l15 = l & 15, l4 = l >> 4;

  // id -> (b, qt, z, ks); batch pinned to an XCD pair for L2 locality
  const int id = blockIdx.x;                 // 0..511
  const int x8 = id & 7;
  const int b  = x8 >> 1;
  const int widx = ((id >> 3) << 1) | (x8 & 1);   // 0..127
  const int qt = widx >> 2;                  // 0..31
  const int z  = (widx >> 1) & 1;
  const int ks = widx & 1;
  const int i0 = qt * 128;
  const int cbase = z * 128;
  const int rowbase = i0 + wv * 16;          // wave's 16 query rows

  const short* Qb = Q + (size_t)b * NT * 64;
  const char*  Kb = (const char*)(K  + (size_t)b * NT * 64);
  const char*  Vb = (const char*)(Vt + (size_t)b * CF * NT);

  // Q fragments (B-operand: col=l15 -> query rowbase+l15, k=l4*8..)
  bf16x8 qf[2];
#pragma unroll
  for (int kk = 0; kk < 2; ++kk)
    qf[kk] = *(const bf16x8*)&Qb[(size_t)(rowbase + l15) * 64 + kk * 32 + l4 * 8];

  // static shift: C-init for QK = -M_i = -sqrt(qnorm2_i * kmax2)
  const float km2 = __uint_as_float(kmax2[b]);
  f32x4 c0;
  {
    float mneg = -sqrtf(qnorm2[(size_t)b * NT + rowbase + l15] * km2);
    c0[0] = mneg; c0[1] = mneg; c0[2] = mneg; c0[3] = mneg;
  }

  const int a32 = ((l ^ 32) << 2);                // bpermute byte index (epilogue)

  // reader per-lane byte offsets (loop-invariant)
  const int kperm = 8 * (l15 >> 2) + (l15 & 3);
  const int swzk = (l15 & 3) | (((l15 >> 2) & 1) << 2);
  const int swzv = (l15 & 3) | (((l15 >> 3) & 1) << 2);
  int baseK[2], baseV[2];
#pragma unroll
  for (int kk = 0; kk < 2; ++kk) {
    baseK[kk] = kperm * 128 + (((kk * 4 + l4) ^ swzk) << 4);
    baseV[kk] = l15 * 128 + (((kk * 4 + l4) ^ swzv) << 4);
  }

  // staging: 24 1KB chunks/tile (K 8, V 16), 3 per wave; linear LDS dest +
  // inverse-swizzled global source (swz = (row&3) | ((row>>3&1)<<2)).
  // Key offset ks*2048 baked into the source pointers.
  const char* sptr[3]; int sinc[3], doff0[3], dadd[3];
#pragma unroll
  for (int i = 0; i < 3; ++i) {
    int c = wv * 3 + i;
    if (c < 8) {              // K chunk: rows 8c..8c+7 (128B rows)
      int r = c * 8 + (l >> 3);
      int sw = (r & 3) | (((r >> 3) & 1) << 2);
      sptr[i] = Kb + (size_t)(ks * 2048 + r) * 128 + (((l & 7) ^ sw) << 4);
      sinc[i] = 8192;         // next 64 keys
      doff0[i] = c * 1024;
      dadd[i] = 8192;
    } else {                  // V chunk: channels 8(c-8)..+7 of wg's 128
      int vr = (c - 8) * 8 + (l >> 3);
      int sw = (vr & 3) | (((vr >> 3) & 1) << 2);
      sptr[i] = Vb + (size_t)(cbase + vr) * (NT * 2) + ks * 4096 + (((l & 7) ^ sw) << 4);
      sinc[i] = 128;          // next 64 keys
      doff0[i] = 16384 + (c - 8) * 1024;
      dadd[i] = 16384;
    }
  }

  // prologue: stage tile 0 into parity 0
#pragma unroll
  for (int i = 0; i < 3; ++i) {
    glds16(sptr[i], arena + doff0[i]);
    sptr[i] += sinc[i];
  }
  __syncthreads();

  f32x4 acc[8] = {};
  float lrow = 0.f;   // per-lane PARTIAL sum (own 16 key-slots)

  for (int jb = 0; jb < 32; ++jb) {
    const int cur = jb & 1;
    const char* Kc = arena + cur * 8192;
    const char* Vc = arena + 16384 + cur * 16384;

    // stage next tile (async; has the whole compute phase to land)
    if (jb < 31) {
      const int p = cur ^ 1;
#pragma unroll
      for (int i = 0; i < 3; ++i) {
        glds16(sptr[i], arena + doff0[i] + p * dadd[i]);
        sptr[i] += sinc[i];
      }
    }

    // K fragments (A-operand, permuted rows)
    bf16x8 kf[4][2];
#pragma unroll
    for (int nj = 0; nj < 4; ++nj) {
      const int ko = (nj >> 1) * 4096 + (nj & 1) * 512;
#pragma unroll
      for (int kk = 0; kk < 2; ++kk)
        kf[nj][kk] = *(const bf16x8*)(Kc + baseK[kk] + ko);
    }

    // S^T = K_perm @ Q^T - M  (static shift folded into C-init)
    f32x4 s[4];
    __builtin_amdgcn_s_setprio(1);
#pragma unroll
    for (int nj = 0; nj < 4; ++nj) {
      s[nj] = __builtin_amdgcn_mfma_f32_16x16x32_bf16(kf[nj][0], qf[0], c0, 0, 0, 0);
      s[nj] = __builtin_amdgcn_mfma_f32_16x16x32_bf16(kf[nj][1], qf[1], s[nj], 0, 0, 0);
    }
    __builtin_amdgcn_s_setprio(0);

    // V fragments (B-operand): wave reads all 128 wg-cols (16 per nv)
    bf16x8 vb[8][2];
#pragma unroll
    for (int nv = 0; nv < 8; ++nv)
#pragma unroll
      for (int kk = 0; kk < 2; ++kk)
        vb[nv][kk] = *(const bf16x8*)(Vc + baseV[kk] + nv * 2048);

    // softmax numerators: p = 2^s (s <= ~0 by the static bound); no reduce,
    // no branch.  Per-lane partial sum accumulates into lrow.
#pragma unroll
    for (int nj = 0; nj < 4; ++nj)
#pragma unroll
      for (int r = 0; r < 4; ++r)
        s[nj][r] = fexp2(s[nj][r]);

    lrow += ((s[0][0] + s[0][1]) + (s[0][2] + s[0][3]))
          + ((s[1][0] + s[1][1]) + (s[1][2] + s[1][3]))
          + ((s[2][0] + s[2][1]) + (s[2][2] + s[2][3]))
          + ((s[3][0] + s[3][1]) + (s[3][2] + s[3][3]));

    unsigned pk[4][2];
#pragma unroll
    for (int nj = 0; nj < 4; ++nj)
#pragma unroll
      for (int h = 0; h < 2; ++h)
        asm("v_cvt_pk_bf16_f32 %0, %1, %2"
            : "=v"(pk[nj][h]) : "v"(s[nj][2 * h]), "v"(s[nj][2 * h + 1]));
    bf16x8 pa[2];
#pragma unroll
    for (int kk = 0; kk < 2; ++kk) {
      union { unsigned u[4]; bf16x8 v; } u;
      u.u[0] = pk[2 * kk][0];     u.u[1] = pk[2 * kk][1];
      u.u[2] = pk[2 * kk + 1][0]; u.u[3] = pk[2 * kk + 1][1];
      pa[kk] = u.v;
    }

    // O += P @ V
    __builtin_amdgcn_s_setprio(1);
#pragma unroll
    for (int kk = 0; kk < 2; ++kk)
#pragma unroll
      for (int nv = 0; nv < 8; ++nv)
        acc[nv] = __builtin_amdgcn_mfma_f32_16x16x32_bf16(pa[kk], vb[nv][kk], acc[nv], 0, 0, 0);
    __builtin_amdgcn_s_setprio(0);

    __syncthreads();   // implicit vmcnt(0): next-tile stage landed; reads done
  }

  // ---- epilogue: atomic-combine partials (2 contributors/elem, exact) ----
  float* Obuf = (float*)(void*)arena + wv * (16 * 68);

  // full row sums for this wave's 16 rows
  float lf = lrow;
  lf += __int_as_float(__builtin_amdgcn_ds_swizzle(__float_as_int(lf), 0x401F));
  lf += __int_as_float(__builtin_amdgcn_ds_bpermute(a32, __float_as_int(lf)));
  if (z == 0 && l < 16)
    atomicAdd(&lpart[(size_t)b * NT + rowbase + l], lf);

  float* Ob = Opart + (size_t)b * CF * NT;
#pragma unroll
  for (int h = 0; h < 2; ++h) {
#pragma unroll
    for (int nv = 0; nv < 4; ++nv)
#pragma unroll
      for (int r = 0; r < 4; ++r)
        Obuf[(4 * l4 + r) * 68 + 16 * nv + l15] = acc[h * 4 + nv][r];
    // same-wave LDS write->read; per-wave disjoint regions, in-order DS
#pragma unroll 4
    for (int t = 0; t < 16; ++t) {
      int c = cbase + h * 64 + l4 + 4 * t;
      size_t off = (size_t)c * NT + rowbase + l15;
      atomicAdd(&Ob[off], Obuf[l15 * 68 + l4 + 4 * t]);
    }
  }
}

// ---------------------------------------------------------------------------
// Finalize: out = gamma * Opart / l + src   (elementwise, vectorized)
// ---------------------------------------------------------------------------
__global__ __launch_bounds__(256, 4)
void finalize_kernel(float* __restrict__ out, const float* __restrict__ src,
                     const float* __restrict__ lpart, const float* __restrict__ gamma_p)
{
  const float g = gamma_p[0];
  size_t e = ((size_t)blockIdx.x * 256 + threadIdx.x) * 4;
  // total elems = 4*256*4096 = 16,777,216; grid covers exactly
  size_t b = e / ((size_t)CF * NT);
  size_t i = e % NT;
  f32x4 o = *(const f32x4*)&out[e];
  f32x4 sv = *(const f32x4*)&src[e];
  f32x4 lv = *(const f32x4*)&lpart[b * NT + i];
  f32x4 res;
#pragma unroll
  for (int t = 0; t < 4; ++t) res[t] = g * o[t] / lv[t] + sv[t];
  *(f32x4*)&out[e] = res;
}

// ---------------------------------------------------------------------------
extern "C" void kernel_launch(void* const* d_in, const int* in_sizes, int n_in,
                              void* d_out, int out_size, void* d_ws, size_t ws_size,
                              hipStream_t stream) {
  const float* src    = (const float*)d_in[0];
  const float* ref    = (const float*)d_in[1];
  const float* w_src  = (const float*)d_in[2];
  const float* b_src  = (const float*)d_in[3];
  const float* w_ref  = (const float*)d_in[4];
  const float* b_ref  = (const float*)d_in[5];
  const float* w_gate = (const float*)d_in[6];
  const float* b_gate = (const float*)d_in[7];
  const float* gamma  = (const float*)d_in[8];
  float* out = (float*)d_out;

  const size_t qk_elems = (size_t)4 * NT * 64;
  const size_t v_elems  = (size_t)4 * CF * NT;
  const size_t base_bytes = (qk_elems * 2 + v_elems) * sizeof(short);
  if (ws_size < base_bytes + 4 * NT * sizeof(float) + 4 * sizeof(unsigned)
                 + 4 * NT * sizeof(float)) return;
  short* Qw = (short*)d_ws;
  short* Kw = Qw + qk_elems;
  short* Vw = Kw + qk_elems;
  float* qnormp = (float*)(Vw + v_elems);
  unsigned* kmaxp = (unsigned*)(qnormp + 4 * NT);
  float* lpart = (float*)(kmaxp + 4);

  // zero: O partial accumulator (= out), kmax2 + lpart (contiguous)
  hipMemsetAsync(out, 0, (size_t)out_size * sizeof(float), stream);
  hipMemsetAsync(kmaxp, 0, 4 * sizeof(unsigned) + 4 * NT * sizeof(float), stream);

  // fold energy scale (1/16) AND log2(e) into Q so scores are log2-domain
  proj_kernel<<<dim3(NT / 64, 4, 2), dim3(256), 0, stream>>>(
      src, ref, w_src, b_src, w_ref, b_ref, w_gate, b_gate,
      Qw, Kw, Vw, qnormp, kmaxp, 0.0625f * 1.44269504f);

  flash_kernel<<<dim3(512), dim3(512), 0, stream>>>(Qw, Kw, Vw, qnormp, kmaxp, out, lpart);

  finalize_kernel<<<dim3((4 * CF * NT) / (256 * 4)), dim3(256), 0, stream>>>(
      out, src, lpart, gamma);
}

// Round 17
// 116.367 us; speedup vs baseline: 2.2343x; 2.2343x over previous
//
#include <hip/hip_runtime.h>
#include <hip/hip_bf16.h>

#define NT 4096      // H*W
#define CF 256       // feature channels
// CQK = 64

typedef __attribute__((ext_vector_type(8))) short bf16x8;
typedef __attribute__((ext_vector_type(4))) float f32x4;
typedef __attribute__((ext_vector_type(4))) short s16x4;

__device__ __forceinline__ short f2bf(float f) {
  union { float f; unsigned u; } v; v.f = f;
  unsigned r = v.u + 0x7FFFu + ((v.u >> 16) & 1u);   // RTNE
  return (short)(r >> 16);
}
__device__ __forceinline__ float bf2f(short s) {
  union { unsigned u; float f; } w; w.u = ((unsigned)(unsigned short)s) << 16;
  return w.f;
}

// async global->LDS, 16B per lane; LDS dest = wave-uniform base + lane*16
__device__ __forceinline__ void glds16(const void* g, void* l) {
  __builtin_amdgcn_global_load_lds(
      (const __attribute__((address_space(1))) void*)g,
      (__attribute__((address_space(3))) void*)l, 16, 0, 0);
}

// bare hardware exp2 (log2-domain scores shifted to <= ~0; finite args)
__device__ __forceinline__ float fexp2(float x) {
  float r;
  asm("v_exp_f32 %0, %1" : "=v"(r) : "v"(x));
  return r;
}

// ---------------------------------------------------------------------------
// Fused projections (one launch, role by blockIdx.z):
// z=0: Q (B,NT,64) = (src.w_src + b)*qscale, + per-row squared norm qnorm2.
// z=1: K (B,NT,64), Vt (B,256,NT) from ONE staging of ref, + kmax2[b].
// ---------------------------------------------------------------------------
__global__ __launch_bounds__(256, 2)
void proj_kernel(const float* __restrict__ src, const float* __restrict__ ref,
                 const float* __restrict__ w_src, const float* __restrict__ b_src,
                 const float* __restrict__ w_ref, const float* __restrict__ b_ref,
                 const float* __restrict__ w_gate, const float* __restrict__ b_gate,
                 short* __restrict__ Qw, short* __restrict__ Kw, short* __restrict__ Vw,
                 float* __restrict__ qnorm2, unsigned* __restrict__ kmax2, float qscale)
{
  __shared__ alignas(16) short Xlds[64 * 256];   // 32KB; reused as norm scratch
  const int tid = threadIdx.x;
  const int wv = tid >> 6, l = tid & 63;
  const int l15 = l & 15, l4 = l >> 4;
  const int i0 = blockIdx.x * 64;
  const int b  = blockIdx.y;
  const bool isref = (blockIdx.z != 0);
  const float* Xb = (isref ? ref : src) + (size_t)b * CF * NT;

#pragma unroll
  for (int it = 0; it < 16; ++it) {
    int c0 = it * 16 + wv * 4;
    float x0 = Xb[(size_t)(c0 + 0) * NT + i0 + l];
    float x1 = Xb[(size_t)(c0 + 1) * NT + i0 + l];
    float x2 = Xb[(size_t)(c0 + 2) * NT + i0 + l];
    float x3 = Xb[(size_t)(c0 + 3) * NT + i0 + l];
    s16x4 pk; pk[0] = f2bf(x0); pk[1] = f2bf(x1); pk[2] = f2bf(x2); pk[3] = f2bf(x3);
    int phys = (l * 512 + c0 * 2) ^ ((l & 31) << 4);
    *(s16x4*)((char*)Xlds + phys) = pk;
  }
  __syncthreads();

  if (!isref) {
    // ---- Q projection + qnorm2 ----
    f32x4 acc[4] = {};
    const int o = wv * 16 + l15;
#pragma unroll
    for (int kk = 0; kk < 8; ++kk) {
      bf16x8 a[4];
#pragma unroll
      for (int mi = 0; mi < 4; ++mi) {
        int i = 16 * mi + l15;
        int phys = (i * 512 + kk * 64 + l4 * 16) ^ ((i & 31) << 4);
        a[mi] = *(const bf16x8*)((const char*)Xlds + phys);
      }
      const float* wp = w_src + (size_t)o * CF + kk * 32 + l4 * 8;
      bf16x8 wf;
#pragma unroll
      for (int t = 0; t < 8; ++t) wf[t] = f2bf(wp[t]);
#pragma unroll
      for (int mi = 0; mi < 4; ++mi)
        acc[mi] = __builtin_amdgcn_mfma_f32_16x16x32_bf16(a[mi], wf, acc[mi], 0, 0, 0);
    }
    __syncthreads();                         // all waves done reading Xlds
    float* nlds = (float*)(void*)Xlds;       // [64][65] padded sq matrix
    const float bv = b_src[o];
#pragma unroll
    for (int mi = 0; mi < 4; ++mi)
#pragma unroll
      for (int r = 0; r < 4; ++r) {
        float val = (acc[mi][r] + bv) * qscale;
        short sv = f2bf(val);
        int row = 16 * mi + l4 * 4 + r;
        Qw[((size_t)b * NT + i0 + row) * 64 + o] = sv;
        float qr = bf2f(sv);
        nlds[row * 65 + o] = qr * qr;
      }
    __syncthreads();
    if (tid < 64) {
      float ss = 0.f;
#pragma unroll 8
      for (int j = 0; j < 64; ++j) ss += nlds[tid * 65 + j];
      qnorm2[(size_t)b * NT + i0 + tid] = ss;
    }
  } else {
    // ---- K + V projections + kmax2 ----
    f32x4 accK[4] = {};
    f32x4 accV[4][4] = {};
    const int oK = wv * 16 + l15;
#pragma unroll
    for (int kk = 0; kk < 8; ++kk) {
      bf16x8 a[4];
#pragma unroll
      for (int mi = 0; mi < 4; ++mi) {
        int i = 16 * mi + l15;
        int phys = (i * 512 + kk * 64 + l4 * 16) ^ ((i & 31) << 4);
        a[mi] = *(const bf16x8*)((const char*)Xlds + phys);
      }
      {
        const float* wp = w_ref + (size_t)oK * CF + kk * 32 + l4 * 8;
        bf16x8 wf;
#pragma unroll
        for (int t = 0; t < 8; ++t) wf[t] = f2bf(wp[t]);
#pragma unroll
        for (int mi = 0; mi < 4; ++mi)
          accK[mi] = __builtin_amdgcn_mfma_f32_16x16x32_bf16(a[mi], wf, accK[mi], 0, 0, 0);
      }
#pragma unroll
      for (int no = 0; no < 4; ++no) {
        int oV = wv * 64 + 16 * no + l15;
        const float* wp = w_gate + (size_t)oV * CF + kk * 32 + l4 * 8;
        bf16x8 wf;
#pragma unroll
        for (int t = 0; t < 8; ++t) wf[t] = f2bf(wp[t]);
#pragma unroll
        for (int mi = 0; mi < 4; ++mi)
          accV[mi][no] = __builtin_amdgcn_mfma_f32_16x16x32_bf16(a[mi], wf, accV[mi][no], 0, 0, 0);
      }
    }

#pragma unroll
    for (int no = 0; no < 4; ++no) {
      int oV = wv * 64 + 16 * no + l15;
      float bv = b_gate[oV];
#pragma unroll
      for (int mi = 0; mi < 4; ++mi) {
        s16x4 pk;
#pragma unroll
        for (int r = 0; r < 4; ++r) pk[r] = f2bf(accV[mi][no][r] + bv);
        *(s16x4*)&Vw[((size_t)b * CF + oV) * NT + i0 + 16 * mi + l4 * 4] = pk;
      }
    }

    __syncthreads();                         // all waves done reading Xlds
    float* nlds = (float*)(void*)Xlds;       // [64][65]
    const float bk = b_ref[oK];
#pragma unroll
    for (int mi = 0; mi < 4; ++mi)
#pragma unroll
      for (int r = 0; r < 4; ++r) {
        float val = accK[mi][r] + bk;
        short sv = f2bf(val);
        int row = 16 * mi + l4 * 4 + r;
        Kw[((size_t)b * NT + i0 + row) * 64 + oK] = sv;
        float qr = bf2f(sv);
        nlds[row * 65 + oK] = qr * qr;
      }
    __syncthreads();
    if (tid < 64) {
      float ss = 0.f;
#pragma unroll 8
      for (int j = 0; j < 64; ++j) ss += nlds[tid * 65 + j];
#pragma unroll
      for (int m = 1; m <= 32; m <<= 1) ss = fmaxf(ss, __shfl_xor(ss, m, 64));
      if (tid == 0) atomicMax(&kmax2[b], __float_as_uint(ss));
    }
  }
}

// ---------------------------------------------------------------------------
// Flash attention partials.  R11 flash body VERBATIM (73.4us proven, 92 VGPR,
// 48KB LDS) + ks key-split across wgs.  wg = 4 waves = 64 q-rows x 128 cols;
// wave = 16 q-rows x 128 cols; ks half = 2048 keys (32 tiles).
// Grid = 64 qt x 2 z x 2 ks x 4 b = 1024 wgs of 256 thr.  Natural residency:
// LDS 48KB -> 3 wg/CU, VGPR ~92 -> 4 waves/SIMD allowed => 12 waves/CU
// (3/SIMD) WITHOUT launch_bounds forcing (R16's spill trap).
// Combine: unnormalized O and row-sums l via f32 atomicAdd -- exactly 2
// contributors per element, commutative -> bit-deterministic.
// STATIC softmax shift (Cauchy-Schwarz) folded into QK C-init.
// ---------------------------------------------------------------------------
__global__ __launch_bounds__(256, 2)
void flash_kernel(const short* __restrict__ Q, const short* __restrict__ K,
                  const short* __restrict__ Vt,
                  const float* __restrict__ qnorm2, const unsigned* __restrict__ kmax2,
                  float* __restrict__ Opart, float* __restrict__ lpart)
{
  // arena: K dbuf 2x8KB at 0; V dbuf 2x16KB at 16384; epilogue reuse.
  __shared__ alignas(16) char arena[49152];

  const int tid = threadIdx.x;
  const int wv = tid >> 6, l = tid & 63;
  const int l15 = l & 15, l4 = l >> 4;

  // id -> (b, qt, z, ks); batch pinned to an XCD pair for L2 locality
  const int id = blockIdx.x;                 // 0..1023
  const int x8 = id & 7;
  const int b  = x8 >> 1;
  const int widx = ((id >> 3) << 1) | (x8 & 1);   // 0..255
  const int qt = widx >> 2;                  // 0..63
  const int z  = (widx >> 1) & 1;
  const int ks = widx & 1;
  const int i0 = qt * 64;
  const int cbase = z * 128;
  const int rowbase = i0 + wv * 16;          // wave's 16 query rows

  const short* Qb = Q + (size_t)b * NT * 64;
  const char*  Kb = (const char*)(K  + (size_t)b * NT * 64);
  const char*  Vb = (const char*)(Vt + (size_t)b * CF * NT);

  // Q fragments (B-operand: col=l15 -> query rowbase+l15, k=l4*8..)
  bf16x8 qf[2];
#pragma unroll
  for (int kk = 0; kk < 2; ++kk)
    qf[kk] = *(const bf16x8*)&Qb[(size_t)(rowbase + l15) * 64 + kk * 32 + l4 * 8];

  // static shift: C-init for QK = -M_i = -sqrt(qnorm2_i * kmax2)
  const float km2 = __uint_as_float(kmax2[b]);
  f32x4 c0;
  {
    float mneg = -sqrtf(qnorm2[(size_t)b * NT + rowbase + l15] * km2);
    c0[0] = mneg; c0[1] = mneg; c0[2] = mneg; c0[3] = mneg;
  }

  const int a32 = ((l ^ 32) << 2);                // bpermute byte index (epilogue)

  // reader per-lane byte offsets (loop-invariant)
  const int kperm = 8 * (l15 >> 2) + (l15 & 3);
  const int swzk = (l15 & 3) | (((l15 >> 2) & 1) << 2);
  const int swzv = (l15 & 3) | (((l15 >> 3) & 1) << 2);
  int baseK[2], baseV[2];
#pragma unroll
  for (int kk = 0; kk < 2; ++kk) {
    baseK[kk] = kperm * 128 + (((kk * 4 + l4) ^ swzk) << 4);
    baseV[kk] = l15 * 128 + (((kk * 4 + l4) ^ swzv) << 4);
  }

  // staging: 24 1KB chunks/tile (K 8, V 16), 6 per wave; linear LDS dest +
  // inverse-swizzled global source (swz = (row&3) | ((row>>3&1)<<2)).
  // Key offset ks*2048 baked into the source pointers (R15-proven).
  const char* sptr[6]; int sinc[6], doff0[6], dadd[6];
#pragma unroll
  for (int i = 0; i < 6; ++i) {
    int c = wv * 6 + i;
    if (c < 8) {              // K chunk: rows 8c..8c+7 (128B rows)
      int r = c * 8 + (l >> 3);
      int sw = (r & 3) | (((r >> 3) & 1) << 2);
      sptr[i] = Kb + (size_t)(ks * 2048 + r) * 128 + (((l & 7) ^ sw) << 4);
      sinc[i] = 8192;         // next 64 keys
      doff0[i] = c * 1024;
      dadd[i] = 8192;
    } else {                  // V chunk: channels 8(c-8)..+7 of wg's 128
      int vr = (c - 8) * 8 + (l >> 3);
      int sw = (vr & 3) | (((vr >> 3) & 1) << 2);
      sptr[i] = Vb + (size_t)(cbase + vr) * (NT * 2) + ks * 4096 + (((l & 7) ^ sw) << 4);
      sinc[i] = 128;          // next 64 keys
      doff0[i] = 16384 + (c - 8) * 1024;
      dadd[i] = 16384;
    }
  }

  // prologue: stage tile 0 into parity 0
#pragma unroll
  for (int i = 0; i < 6; ++i) {
    glds16(sptr[i], arena + doff0[i]);
    sptr[i] += sinc[i];
  }
  __syncthreads();

  f32x4 acc[8] = {};
  float lrow = 0.f;   // per-lane PARTIAL sum (own 16 key-slots)

  for (int jb = 0; jb < 32; ++jb) {
    const int cur = jb & 1;
    const char* Kc = arena + cur * 8192;
    const char* Vc = arena + 16384 + cur * 16384;

    // stage next tile (async; has the whole compute phase to land)
    if (jb < 31) {
      const int p = cur ^ 1;
#pragma unroll
      for (int i = 0; i < 6; ++i) {
        glds16(sptr[i], arena + doff0[i] + p * dadd[i]);
        sptr[i] += sinc[i];
      }
    }

    // K fragments (A-operand, permuted rows)
    bf16x8 kf[4][2];
#pragma unroll
    for (int nj = 0; nj < 4; ++nj) {
      const int ko = (nj >> 1) * 4096 + (nj & 1) * 512;
#pragma unroll
      for (int kk = 0; kk < 2; ++kk)
        kf[nj][kk] = *(const bf16x8*)(Kc + baseK[kk] + ko);
    }

    // S^T = K_perm @ Q^T - M  (static shift folded into C-init)
    f32x4 s[4];
    __builtin_amdgcn_s_setprio(1);
#pragma unroll
    for (int nj = 0; nj < 4; ++nj) {
      s[nj] = __builtin_amdgcn_mfma_f32_16x16x32_bf16(kf[nj][0], qf[0], c0, 0, 0, 0);
      s[nj] = __builtin_amdgcn_mfma_f32_16x16x32_bf16(kf[nj][1], qf[1], s[nj], 0, 0, 0);
    }
    __builtin_amdgcn_s_setprio(0);

    // V fragments (B-operand): wave reads all 128 wg-cols (16 per nv)
    bf16x8 vb[8][2];
#pragma unroll
    for (int nv = 0; nv < 8; ++nv)
#pragma unroll
      for (int kk = 0; kk < 2; ++kk)
        vb[nv][kk] = *(const bf16x8*)(Vc + baseV[kk] + nv * 2048);

    // softmax numerators: p = 2^s (s <= ~0 by the static bound); no reduce,
    // no branch.  Per-lane partial sum accumulates into lrow.
#pragma unroll
    for (int nj = 0; nj < 4; ++nj)
#pragma unroll
      for (int r = 0; r < 4; ++r)
        s[nj][r] = fexp2(s[nj][r]);

    lrow += ((s[0][0] + s[0][1]) + (s[0][2] + s[0][3]))
          + ((s[1][0] + s[1][1]) + (s[1][2] + s[1][3]))
          + ((s[2][0] + s[2][1]) + (s[2][2] + s[2][3]))
          + ((s[3][0] + s[3][1]) + (s[3][2] + s[3][3]));

    unsigned pk[4][2];
#pragma unroll
    for (int nj = 0; nj < 4; ++nj)
#pragma unroll
      for (int h = 0; h < 2; ++h)
        asm("v_cvt_pk_bf16_f32 %0, %1, %2"
            : "=v"(pk[nj][h]) : "v"(s[nj][2 * h]), "v"(s[nj][2 * h + 1]));
    bf16x8 pa[2];
#pragma unroll
    for (int kk = 0; kk < 2; ++kk) {
      union { unsigned u[4]; bf16x8 v; } u;
      u.u[0] = pk[2 * kk][0];     u.u[1] = pk[2 * kk][1];
      u.u[2] = pk[2 * kk + 1][0]; u.u[3] = pk[2 * kk + 1][1];
      pa[kk] = u.v;
    }

    // O += P @ V
    __builtin_amdgcn_s_setprio(1);
#pragma unroll
    for (int kk = 0; kk < 2; ++kk)
#pragma unroll
      for (int nv = 0; nv < 8; ++nv)
        acc[nv] = __builtin_amdgcn_mfma_f32_16x16x32_bf16(pa[kk], vb[nv][kk], acc[nv], 0, 0, 0);
    __builtin_amdgcn_s_setprio(0);

    __syncthreads();   // implicit vmcnt(0): next-tile stage landed; reads done
  }

  // ---- epilogue: atomic-combine partials (2 contributors/elem, exact) ----
  float* Obuf = (float*)(void*)arena + wv * (16 * 132);

  // full row sums for this wave's 16 rows
  float lf = lrow;
  lf += __int_as_float(__builtin_amdgcn_ds_swizzle(__float_as_int(lf), 0x401F));
  lf += __int_as_float(__builtin_amdgcn_ds_bpermute(a32, __float_as_int(lf)));
  if (z == 0 && l < 16)
    atomicAdd(&lpart[(size_t)b * NT + rowbase + l], lf);

  float* Ob = Opart + (size_t)b * CF * NT;
#pragma unroll
  for (int nv = 0; nv < 8; ++nv)
#pragma unroll
    for (int r = 0; r < 4; ++r)
      Obuf[(4 * l4 + r) * 132 + 16 * nv + l15] = acc[nv][r];
  // same-wave LDS write->read; per-wave disjoint regions, in-order DS
#pragma unroll 4
  for (int t = 0; t < 32; ++t) {
    int c = cbase + l4 + 4 * t;
    size_t off = (size_t)c * NT + rowbase + l15;
    atomicAdd(&Ob[off], Obuf[l15 * 132 + l4 + 4 * t]);
  }
}

// ---------------------------------------------------------------------------
// Finalize: out = gamma * Opart / l + src   (elementwise, vectorized)
// ---------------------------------------------------------------------------
__global__ __launch_bounds__(256, 4)
void finalize_kernel(float* __restrict__ out, const float* __restrict__ src,
                     const float* __restrict__ lpart, const float* __restrict__ gamma_p)
{
  const float g = gamma_p[0];
  size_t e = ((size_t)blockIdx.x * 256 + threadIdx.x) * 4;
  size_t b = e / ((size_t)CF * NT);
  size_t i = e % NT;
  f32x4 o = *(const f32x4*)&out[e];
  f32x4 sv = *(const f32x4*)&src[e];
  f32x4 lv = *(const f32x4*)&lpart[b * NT + i];
  f32x4 res;
#pragma unroll
  for (int t = 0; t < 4; ++t) res[t] = g * o[t] / lv[t] + sv[t];
  *(f32x4*)&out[e] = res;
}

// ---------------------------------------------------------------------------
extern "C" void kernel_launch(void* const* d_in, const int* in_sizes, int n_in,
                              void* d_out, int out_size, void* d_ws, size_t ws_size,
                              hipStream_t stream) {
  const float* src    = (const float*)d_in[0];
  const float* ref    = (const float*)d_in[1];
  const float* w_src  = (const float*)d_in[2];
  const float* b_src  = (const float*)d_in[3];
  const float* w_ref  = (const float*)d_in[4];
  const float* b_ref  = (const float*)d_in[5];
  const float* w_gate = (const float*)d_in[6];
  const float* b_gate = (const float*)d_in[7];
  const float* gamma  = (const float*)d_in[8];
  float* out = (float*)d_out;

  const size_t qk_elems = (size_t)4 * NT * 64;
  const size_t v_elems  = (size_t)4 * CF * NT;
  const size_t base_bytes = (qk_elems * 2 + v_elems) * sizeof(short);
  if (ws_size < base_bytes + 4 * NT * sizeof(float) + 4 * sizeof(unsigned)
                 + 4 * NT * sizeof(float)) return;
  short* Qw = (short*)d_ws;
  short* Kw = Qw + qk_elems;
  short* Vw = Kw + qk_elems;
  float* qnormp = (float*)(Vw + v_elems);
  unsigned* kmaxp = (unsigned*)(qnormp + 4 * NT);
  float* lpart = (float*)(kmaxp + 4);

  // zero: O partial accumulator (= out), kmax2 + lpart (contiguous)
  hipMemsetAsync(out, 0, (size_t)out_size * sizeof(float), stream);
  hipMemsetAsync(kmaxp, 0, 4 * sizeof(unsigned) + 4 * NT * sizeof(float), stream);

  // fold energy scale (1/16) AND log2(e) into Q so scores are log2-domain
  proj_kernel<<<dim3(NT / 64, 4, 2), dim3(256), 0, stream>>>(
      src, ref, w_src, b_src, w_ref, b_ref, w_gate, b_gate,
      Qw, Kw, Vw, qnormp, kmaxp, 0.0625f * 1.44269504f);

  flash_kernel<<<dim3(1024), dim3(256), 0, stream>>>(Qw, Kw, Vw, qnormp, kmaxp, out, lpart);

  finalize_kernel<<<dim3((4 * CF * NT) / (256 * 4)), dim3(256), 0, stream>>>(
      out, src, lpart, gamma);
}

// Round 18
// 69.637 us; speedup vs baseline: 3.7337x; 1.6711x over previous
//
#include <hip/hip_runtime.h>
#include <hip/hip_bf16.h>

#define NT 4096      // H*W
#define CF 256       // feature channels
// CQK = 64

typedef __attribute__((ext_vector_type(8))) short bf16x8;
typedef __attribute__((ext_vector_type(4))) float f32x4;
typedef __attribute__((ext_vector_type(4))) short s16x4;

__device__ __forceinline__ short f2bf(float f) {
  union { float f; unsigned u; } v; v.f = f;
  unsigned r = v.u + 0x7FFFu + ((v.u >> 16) & 1u);   // RTNE
  return (short)(r >> 16);
}
__device__ __forceinline__ float bf2f(short s) {
  union { unsigned u; float f; } w; w.u = ((unsigned)(unsigned short)s) << 16;
  return w.f;
}

// async global->LDS, 16B per lane; LDS dest = wave-uniform base + lane*16
__device__ __forceinline__ void glds16(const void* g, void* l) {
  __builtin_amdgcn_global_load_lds(
      (const __attribute__((address_space(1))) void*)g,
      (__attribute__((address_space(3))) void*)l, 16, 0, 0);
}

// bare hardware exp2 (log2-domain scores shifted to <= ~0; finite args)
__device__ __forceinline__ float fexp2(float x) {
  float r;
  asm("v_exp_f32 %0, %1" : "=v"(r) : "v"(x));
  return r;
}

// ---------------------------------------------------------------------------
// Fused projections (one launch, role by blockIdx.z):
// z=0: Q (B,NT,64) = (src.w_src + b)*qscale, + per-row squared norm qnorm2.
// z=1: K (B,NT,64), Vt (B,256,NT) from ONE staging of ref, + kmax2[b].
// ---------------------------------------------------------------------------
__global__ __launch_bounds__(256, 2)
void proj_kernel(const float* __restrict__ src, const float* __restrict__ ref,
                 const float* __restrict__ w_src, const float* __restrict__ b_src,
                 const float* __restrict__ w_ref, const float* __restrict__ b_ref,
                 const float* __restrict__ w_gate, const float* __restrict__ b_gate,
                 short* __restrict__ Qw, short* __restrict__ Kw, short* __restrict__ Vw,
                 float* __restrict__ qnorm2, unsigned* __restrict__ kmax2, float qscale)
{
  __shared__ alignas(16) short Xlds[64 * 256];   // 32KB; reused as norm scratch
  const int tid = threadIdx.x;
  const int wv = tid >> 6, l = tid & 63;
  const int l15 = l & 15, l4 = l >> 4;
  const int i0 = blockIdx.x * 64;
  const int b  = blockIdx.y;
  const bool isref = (blockIdx.z != 0);
  const float* Xb = (isref ? ref : src) + (size_t)b * CF * NT;

#pragma unroll
  for (int it = 0; it < 16; ++it) {
    int c0 = it * 16 + wv * 4;
    float x0 = Xb[(size_t)(c0 + 0) * NT + i0 + l];
    float x1 = Xb[(size_t)(c0 + 1) * NT + i0 + l];
    float x2 = Xb[(size_t)(c0 + 2) * NT + i0 + l];
    float x3 = Xb[(size_t)(c0 + 3) * NT + i0 + l];
    s16x4 pk; pk[0] = f2bf(x0); pk[1] = f2bf(x1); pk[2] = f2bf(x2); pk[3] = f2bf(x3);
    int phys = (l * 512 + c0 * 2) ^ ((l & 31) << 4);
    *(s16x4*)((char*)Xlds + phys) = pk;
  }
  __syncthreads();

  if (!isref) {
    f32x4 acc[4] = {};
    const int o = wv * 16 + l15;
#pragma unroll
    for (int kk = 0; kk < 8; ++kk) {
      bf16x8 a[4];
#pragma unroll
      for (int mi = 0; mi < 4; ++mi) {
        int i = 16 * mi + l15;
        int phys = (i * 512 + kk * 64 + l4 * 16) ^ ((i & 31) << 4);
        a[mi] = *(const bf16x8*)((const char*)Xlds + phys);
      }
      const float* wp = w_src + (size_t)o * CF + kk * 32 + l4 * 8;
      bf16x8 wf;
#pragma unroll
      for (int t = 0; t < 8; ++t) wf[t] = f2bf(wp[t]);
#pragma unroll
      for (int mi = 0; mi < 4; ++mi)
        acc[mi] = __builtin_amdgcn_mfma_f32_16x16x32_bf16(a[mi], wf, acc[mi], 0, 0, 0);
    }
    __syncthreads();
    float* nlds = (float*)(void*)Xlds;       // [64][65] padded sq matrix
    const float bv = b_src[o];
#pragma unroll
    for (int mi = 0; mi < 4; ++mi)
#pragma unroll
      for (int r = 0; r < 4; ++r) {
        float val = (acc[mi][r] + bv) * qscale;
        short sv = f2bf(val);
        int row = 16 * mi + l4 * 4 + r;
        Qw[((size_t)b * NT + i0 + row) * 64 + o] = sv;
        float qr = bf2f(sv);
        nlds[row * 65 + o] = qr * qr;
      }
    __syncthreads();
    if (tid < 64) {
      float ss = 0.f;
#pragma unroll 8
      for (int j = 0; j < 64; ++j) ss += nlds[tid * 65 + j];
      qnorm2[(size_t)b * NT + i0 + tid] = ss;
    }
  } else {
    f32x4 accK[4] = {};
    f32x4 accV[4][4] = {};
    const int oK = wv * 16 + l15;
#pragma unroll
    for (int kk = 0; kk < 8; ++kk) {
      bf16x8 a[4];
#pragma unroll
      for (int mi = 0; mi < 4; ++mi) {
        int i = 16 * mi + l15;
        int phys = (i * 512 + kk * 64 + l4 * 16) ^ ((i & 31) << 4);
        a[mi] = *(const bf16x8*)((const char*)Xlds + phys);
      }
      {
        const float* wp = w_ref + (size_t)oK * CF + kk * 32 + l4 * 8;
        bf16x8 wf;
#pragma unroll
        for (int t = 0; t < 8; ++t) wf[t] = f2bf(wp[t]);
#pragma unroll
        for (int mi = 0; mi < 4; ++mi)
          accK[mi] = __builtin_amdgcn_mfma_f32_16x16x32_bf16(a[mi], wf, accK[mi], 0, 0, 0);
      }
#pragma unroll
      for (int no = 0; no < 4; ++no) {
        int oV = wv * 64 + 16 * no + l15;
        const float* wp = w_gate + (size_t)oV * CF + kk * 32 + l4 * 8;
        bf16x8 wf;
#pragma unroll
        for (int t = 0; t < 8; ++t) wf[t] = f2bf(wp[t]);
#pragma unroll
        for (int mi = 0; mi < 4; ++mi)
          accV[mi][no] = __builtin_amdgcn_mfma_f32_16x16x32_bf16(a[mi], wf, accV[mi][no], 0, 0, 0);
      }
    }

#pragma unroll
    for (int no = 0; no < 4; ++no) {
      int oV = wv * 64 + 16 * no + l15;
      float bv = b_gate[oV];
#pragma unroll
      for (int mi = 0; mi < 4; ++mi) {
        s16x4 pk;
#pragma unroll
        for (int r = 0; r < 4; ++r) pk[r] = f2bf(accV[mi][no][r] + bv);
        *(s16x4*)&Vw[((size_t)b * CF + oV) * NT + i0 + 16 * mi + l4 * 4] = pk;
      }
    }

    __syncthreads();
    float* nlds = (float*)(void*)Xlds;       // [64][65]
    const float bk = b_ref[oK];
#pragma unroll
    for (int mi = 0; mi < 4; ++mi)
#pragma unroll
      for (int r = 0; r < 4; ++r) {
        float val = accK[mi][r] + bk;
        short sv = f2bf(val);
        int row = 16 * mi + l4 * 4 + r;
        Kw[((size_t)b * NT + i0 + row) * 64 + oK] = sv;
        float qr = bf2f(sv);
        nlds[row * 65 + oK] = qr * qr;
      }
    __syncthreads();
    if (tid < 64) {
      float ss = 0.f;
#pragma unroll 8
      for (int j = 0; j < 64; ++j) ss += nlds[tid * 65 + j];
#pragma unroll
      for (int m = 1; m <= 32; m <<= 1) ss = fmaxf(ss, __shfl_xor(ss, m, 64));
      if (tid == 0) atomicMax(&kmax2[b], __float_as_uint(ss));
    }
  }
}

// ---------------------------------------------------------------------------
// Flash attention + residual.  KVBLK=32, LDS-staged K/V (global_load_lds,
// dbuf), TWO in-wg key streams: 8 waves = 4 wr x 2 ks; wave = 16 q-rows x
// 128 cols x its 2048-key half.  LDS = 48KB/wg -> 2 wg/CU (96 <= ~128KB
// effective) = 16 waves/CU -- the occupancy lever; no global combine.
// kappa for 32 keys: key = 4*nj + 8*l4 + r (nj in {0,1}).
// ks-partials merged through LDS at the end (exact f32 adds), ks=0 waves
// run the R11-proven normalize+transpose+residual epilogue.
// Arena 48KB: K s0 [0,8K) s1 [8K,16K) (2x4K each); V s0 [16K,32K) s1
// [32K,48K) (2x8K each; 64B rows, 2-bit XOR granule swizzle).
// ---------------------------------------------------------------------------
__global__ __launch_bounds__(256, 2)
void flash_kernel(const short* __restrict__ Q, const short* __restrict__ K,
                  const short* __restrict__ Vt, const float* __restrict__ src,
                  const float* __restrict__ gamma_p,
                  const float* __restrict__ qnorm2, const unsigned* __restrict__ kmax2,
                  float* __restrict__ out)
{
  __shared__ alignas(16) char arena[49152];

  const int tid = threadIdx.x;
  const int wv = tid >> 6, l = tid & 63;
  const int l15 = l & 15, l4 = l >> 4;
  const int wr = wv & 3, ksw = wv >> 2;

  // id -> (b, qt, z); batch pinned to an XCD pair for L2 locality
  const int id = blockIdx.x;                 // 0..511
  const int x8 = id & 7;
  const int b  = x8 >> 1;
  const int widx = ((id >> 3) << 1) | (x8 & 1);   // 0..127
  const int qt = widx >> 1, z = widx & 1;
  const int i0 = qt * 64;
  const int cbase = z * 128;
  const int rowbase = i0 + wr * 16;          // wave's 16 query rows

  const short* Qb = Q + (size_t)b * NT * 64;
  const char*  Kb = (const char*)(K  + (size_t)b * NT * 64);
  const char*  Vb = (const char*)(Vt + (size_t)b * CF * NT);

  // Q fragments (B-operand: col=l15 -> query rowbase+l15, k=l4*8..)
  bf16x8 qf[2];
#pragma unroll
  for (int kk = 0; kk < 2; ++kk)
    qf[kk] = *(const bf16x8*)&Qb[(size_t)(rowbase + l15) * 64 + kk * 32 + l4 * 8];

  // static shift: C-init for QK = -M_i = -sqrt(qnorm2_i * kmax2)
  const float km2 = __uint_as_float(kmax2[b]);
  f32x4 c0;
  {
    float mneg = -sqrtf(qnorm2[(size_t)b * NT + rowbase + l15] * km2);
    c0[0] = mneg; c0[1] = mneg; c0[2] = mneg; c0[3] = mneg;
  }

  const int a32 = ((l ^ 32) << 2);                // bpermute byte index (epilogue)

  // K reader per-lane byte offsets (loop-invariant); rows 0..31
  const int kperm = 8 * (l15 >> 2) + (l15 & 3);
  const int swzk = (l15 & 3) | (((l15 >> 2) & 1) << 2);
  int baseK[2];
#pragma unroll
  for (int kk = 0; kk < 2; ++kk)
    baseK[kk] = kperm * 128 + (((kk * 4 + l4) ^ swzk) << 4);
  // V reader: row = 16nv+l15 (64B rows), granule = l4 ^ (l15&3)
  const int baseV = l15 * 64 + ((l4 ^ (l15 & 3)) << 4);

  // staging: 24 1KB chunks/step (2 streams x (K 4 + V 8)), 3 per wave;
  // linear LDS dest + inverse-swizzled global source.
  const char* sptr[3]; int sinc[3], doff0[3], dadd[3];
#pragma unroll
  for (int i = 0; i < 3; ++i) {
    int c = wv * 3 + i;          // 0..23
    int s = (c >= 12) ? 1 : 0;
    int cc = c - s * 12;
    if (cc < 4) {                // K chunk: tile-rows 8cc..8cc+7 (128B rows)
      int r = cc * 8 + (l >> 3);
      int sw = (r & 3) | (((r >> 3) & 1) << 2);
      sptr[i] = Kb + (size_t)(s * 2048 + r) * 128 + (((l & 7) ^ sw) << 4);
      sinc[i] = 4096;            // next 32 keys
      doff0[i] = s * 8192 + cc * 1024;
      dadd[i] = 4096;
    } else {                     // V chunk: channels 16(cc-4)..+15 (64B rows)
      int cv = cc - 4;           // 0..7
      int vr = cv * 16 + (l >> 2);
      int sw = vr & 3;
      sptr[i] = Vb + (size_t)(cbase + vr) * (NT * 2) + s * 4096 + (((l & 3) ^ sw) << 4);
      sinc[i] = 64;              // next 32 keys
      doff0[i] = 16384 + s * 16384 + cv * 1024;
      dadd[i] = 8192;
    }
  }

  // prologue: stage step 0 (both streams) into parity 0
#pragma unroll
  for (int i = 0; i < 3; ++i) {
    glds16(sptr[i], arena + doff0[i]);
    sptr[i] += sinc[i];
  }
  __syncthreads();

  f32x4 acc[8] = {};
  float lrow = 0.f;   // per-lane PARTIAL sum (own key-slots, own ks-half)

  for (int jb = 0; jb < 64; ++jb) {
    const int cur = jb & 1;
    const char* Kc = arena + ksw * 8192 + cur * 4096;
    const char* Vc = arena + 16384 + ksw * 16384 + cur * 8192;

    // stage next step (async; has the whole compute phase to land)
    if (jb < 63) {
      const int p = cur ^ 1;
#pragma unroll
      for (int i = 0; i < 3; ++i) {
        glds16(sptr[i], arena + doff0[i] + p * dadd[i]);
        sptr[i] += sinc[i];
      }
    }

    // K fragments (A-operand, permuted rows: key = 4*nj + kperm-slot)
    bf16x8 kf[2][2];
#pragma unroll
    for (int nj = 0; nj < 2; ++nj)
#pragma unroll
      for (int kk = 0; kk < 2; ++kk)
        kf[nj][kk] = *(const bf16x8*)(Kc + baseK[kk] + nj * 512);

    // S^T = K_perm @ Q^T - M  (static shift folded into C-init)
    f32x4 s[2];
    __builtin_amdgcn_s_setprio(1);
#pragma unroll
    for (int nj = 0; nj < 2; ++nj) {
      s[nj] = __builtin_amdgcn_mfma_f32_16x16x32_bf16(kf[nj][0], qf[0], c0, 0, 0, 0);
      s[nj] = __builtin_amdgcn_mfma_f32_16x16x32_bf16(kf[nj][1], qf[1], s[nj], 0, 0, 0);
    }
    __builtin_amdgcn_s_setprio(0);

    // V fragments (B-operand): wave reads all 128 wg-cols (16 per nv)
    bf16x8 vb[8];
#pragma unroll
    for (int nv = 0; nv < 8; ++nv)
      vb[nv] = *(const bf16x8*)(Vc + baseV + nv * 1024);

    // softmax numerators: p = 2^s; no reduce, no branch.
#pragma unroll
    for (int nj = 0; nj < 2; ++nj)
#pragma unroll
      for (int r = 0; r < 4; ++r)
        s[nj][r] = fexp2(s[nj][r]);

    lrow += ((s[0][0] + s[0][1]) + (s[0][2] + s[0][3]))
          + ((s[1][0] + s[1][1]) + (s[1][2] + s[1][3]));

    // pack P: key(s[nj][r]) = 4*nj + 8*l4 + r -> pa element t = 4*nj + r
    unsigned pk[2][2];
#pragma unroll
    for (int nj = 0; nj < 2; ++nj)
#pragma unroll
      for (int h = 0; h < 2; ++h)
        asm("v_cvt_pk_bf16_f32 %0, %1, %2"
            : "=v"(pk[nj][h]) : "v"(s[nj][2 * h]), "v"(s[nj][2 * h + 1]));
    bf16x8 pa;
    {
      union { unsigned u[4]; bf16x8 v; } u;
      u.u[0] = pk[0][0]; u.u[1] = pk[0][1];
      u.u[2] = pk[1][0]; u.u[3] = pk[1][1];
      pa = u.v;
    }

    // O += P @ V  (single K=32 slab)
    __builtin_amdgcn_s_setprio(1);
#pragma unroll
    for (int nv = 0; nv < 8; ++nv)
      acc[nv] = __builtin_amdgcn_mfma_f32_16x16x32_bf16(pa, vb[nv], acc[nv], 0, 0, 0);
    __builtin_amdgcn_s_setprio(0);

    __syncthreads();   // implicit vmcnt(0): next-step stage landed; reads done
  }

  // ---- merge key-stream partials through LDS (exact f32 adds) ----
  float* ashare = (float*)(void*)arena;            // 4 x 64 lanes x 33 f32
  float* lshare = (float*)(void*)(arena + 33792);  // 4 x 64 f32

  if (ksw == 1) {
    float* d = ashare + (wr * 64 + l) * 33;
#pragma unroll
    for (int nv = 0; nv < 8; ++nv)
#pragma unroll
      for (int r = 0; r < 4; ++r) d[nv * 4 + r] = acc[nv][r];
    lshare[wr * 64 + l] = lrow;
  }
  __syncthreads();
  if (ksw == 0) {
    const float* s2 = ashare + (wr * 64 + l) * 33;
#pragma unroll
    for (int nv = 0; nv < 8; ++nv)
#pragma unroll
      for (int r = 0; r < 4; ++r) acc[nv][r] += s2[nv * 4 + r];
    lrow += lshare[wr * 64 + l];
  }
  __syncthreads();   // all merge reads done before arena reuse (Obuf)

  if (ksw == 0) {
    // ---- epilogue: reduce row sums, normalize, transpose, residual ----
    float* Obuf = (float*)(void*)arena + wr * (16 * 132);
    const float gm = gamma_p[0];
    const float* srcb = src + (size_t)b * CF * NT;
    float* outb = out + (size_t)b * CF * NT;

    float lf = lrow;
    lf += __int_as_float(__builtin_amdgcn_ds_swizzle(__float_as_int(lf), 0x401F));
    lf += __int_as_float(__builtin_amdgcn_ds_bpermute(a32, __float_as_int(lf)));
    float li[4];
#pragma unroll
    for (int r = 0; r < 4; ++r)
      li[r] = 1.0f / __shfl(lf, 4 * l4 + r, 64);
#pragma unroll
    for (int nv = 0; nv < 8; ++nv)
#pragma unroll
      for (int r = 0; r < 4; ++r)
        Obuf[(4 * l4 + r) * 132 + 16 * nv + l15] = acc[nv][r] * li[r];
    // same-wave LDS write->read; per-wave disjoint regions, in-order DS
#pragma unroll 4
    for (int t = 0; t < 32; ++t) {
      int c = cbase + l4 + 4 * t;
      size_t off = (size_t)c * NT + rowbase + l15;
      float v = Obuf[l15 * 132 + l4 + 4 * t];
      outb[off] = gm * v + srcb[off];
    }
  }
}

// ---------------------------------------------------------------------------
extern "C" void kernel_launch(void* const* d_in, const int* in_sizes, int n_in,
                              void* d_out, int out_size, void* d_ws, size_t ws_size,
                              hipStream_t stream) {
  const float* src    = (const float*)d_in[0];
  const float* ref    = (const float*)d_in[1];
  const float* w_src  = (const float*)d_in[2];
  const float* b_src  = (const float*)d_in[3];
  const float* w_ref  = (const float*)d_in[4];
  const float* b_ref  = (const float*)d_in[5];
  const float* w_gate = (const float*)d_in[6];
  const float* b_gate = (const float*)d_in[7];
  const float* gamma  = (const float*)d_in[8];
  float* out = (float*)d_out;

  const size_t qk_elems = (size_t)4 * NT * 64;
  const size_t v_elems  = (size_t)4 * CF * NT;
  const size_t base_bytes = (qk_elems * 2 + v_elems) * sizeof(short);
  if (ws_size < base_bytes + 4 * NT * sizeof(float) + 4 * sizeof(unsigned)) return;
  short* Qw = (short*)d_ws;
  short* Kw = Qw + qk_elems;
  short* Vw = Kw + qk_elems;
  float* qnormp = (float*)(Vw + v_elems);
  unsigned* kmaxp = (unsigned*)(qnormp + 4 * NT);

  hipMemsetAsync(kmaxp, 0, 4 * sizeof(unsigned), stream);

  // fold energy scale (1/16) AND log2(e) into Q so scores are log2-domain
  proj_kernel<<<dim3(NT / 64, 4, 2), dim3(256), 0, stream>>>(
      src, ref, w_src, b_src, w_ref, b_ref, w_gate, b_gate,
      Qw, Kw, Vw, qnormp, kmaxp, 0.0625f * 1.44269504f);

  flash_kernel<<<dim3(512), dim3(256), 0, stream>>>(Qw, Kw, Vw, src, gamma, qnormp, kmaxp, out);
}